// Round 1
// baseline (1032.308 us; speedup 1.0000x reference)
//
#include <hip/hip_runtime.h>
#include <stdint.h>
#include <stddef.h>

typedef __bf16 bf16_t;
typedef __bf16 bf16x4 __attribute__((ext_vector_type(4)));
typedef __bf16 bf16x8 __attribute__((ext_vector_type(8)));
typedef float f32x4 __attribute__((ext_vector_type(4)));

#define DEV static __device__ __forceinline__

static constexpr int kB = 8, kT = 1024, kC = 1024, kM = 8192, kH = 16, kHD = 64, kFF = 4096;

DEV f32x4 mfma16(bf16x8 a, bf16x8 b, f32x4 c) {
  return __builtin_amdgcn_mfma_f32_16x16x32_bf16(a, b, c, 0, 0, 0);
}

// async global->LDS, 16B per lane. LDS dest must be wave-uniform base (+lane*16 by HW).
DEV void gload_lds16(const void* g, void* l) {
  __builtin_amdgcn_global_load_lds(
      reinterpret_cast<const __attribute__((address_space(1))) void*>(
          reinterpret_cast<uintptr_t>(g)),
      reinterpret_cast<__attribute__((address_space(3))) void*>(
          static_cast<uint32_t>(reinterpret_cast<uintptr_t>(l))),
      16, 0, 0);
}

// ---------------- cast f32 -> bf16 ----------------
__global__ void k_cast_bf16(const float* __restrict__ in, bf16_t* __restrict__ out, int n4) {
  int i = blockIdx.x * blockDim.x + threadIdx.x;
  if (i >= n4) return;
  float4 v = reinterpret_cast<const float4*>(in)[i];
  bf16x4 o;
  o[0] = (bf16_t)v.x; o[1] = (bf16_t)v.y; o[2] = (bf16_t)v.z; o[3] = (bf16_t)v.w;
  reinterpret_cast<bf16x4*>(out)[i] = o;
}

// ---------- transpose+cast f32[R][C] -> bf16[C][R] ----------
__global__ void k_transpose_cast(const float* __restrict__ in, bf16_t* __restrict__ out,
                                 int R, int C) {
  __shared__ float tile[32][33];
  int c0 = blockIdx.x * 32, r0 = blockIdx.y * 32;
  int tx = threadIdx.x, ty = threadIdx.y;  // (32,8)
#pragma unroll
  for (int i = 0; i < 4; ++i)
    tile[ty + 8 * i][tx] = in[(size_t)(r0 + ty + 8 * i) * C + c0 + tx];
  __syncthreads();
#pragma unroll
  for (int i = 0; i < 4; ++i)
    out[(size_t)(c0 + ty + 8 * i) * R + r0 + tx] = (bf16_t)tile[tx][ty + 8 * i];
}

// ---------- transpose bf16[R][C] -> bf16[C][R] ----------
__global__ void k_transpose_bf16(const bf16_t* __restrict__ in, bf16_t* __restrict__ out,
                                 int R, int C) {
  __shared__ bf16_t tile[32][33];
  int c0 = blockIdx.x * 32, r0 = blockIdx.y * 32;
  int tx = threadIdx.x, ty = threadIdx.y;
#pragma unroll
  for (int i = 0; i < 4; ++i)
    tile[ty + 8 * i][tx] = in[(size_t)(r0 + ty + 8 * i) * C + c0 + tx];
  __syncthreads();
#pragma unroll
  for (int i = 0; i < 4; ++i)
    out[(size_t)(c0 + ty + 8 * i) * R + r0 + tx] = tile[tx][ty + 8 * i];
}

// ---------------- layernorm f32 -> bf16 (one block per row of 1024) ----------------
__global__ __launch_bounds__(256) void k_ln(const float* __restrict__ in,
                                            const float* __restrict__ g,
                                            const float* __restrict__ b,
                                            bf16_t* __restrict__ out) {
  int row = blockIdx.x, t = threadIdx.x;
  const float4 v = reinterpret_cast<const float4*>(in + (size_t)row * kC)[t];
  float s = v.x + v.y + v.z + v.w;
  float ss = v.x * v.x + v.y * v.y + v.z * v.z + v.w * v.w;
#pragma unroll
  for (int off = 1; off < 64; off <<= 1) {
    s += __shfl_xor(s, off, 64);
    ss += __shfl_xor(ss, off, 64);
  }
  __shared__ float rs[4], rss[4];
  int w = t >> 6;
  if ((t & 63) == 0) { rs[w] = s; rss[w] = ss; }
  __syncthreads();
  s = rs[0] + rs[1] + rs[2] + rs[3];
  ss = rss[0] + rss[1] + rss[2] + rss[3];
  float mean = s * (1.f / kC);
  float var = ss * (1.f / kC) - mean * mean;
  float rstd = rsqrtf(var + 1e-5f);
  float4 gv = reinterpret_cast<const float4*>(g)[t];
  float4 bv = reinterpret_cast<const float4*>(b)[t];
  bf16x4 o;
  o[0] = (bf16_t)((v.x - mean) * rstd * gv.x + bv.x);
  o[1] = (bf16_t)((v.y - mean) * rstd * gv.y + bv.y);
  o[2] = (bf16_t)((v.z - mean) * rstd * gv.z + bv.z);
  o[3] = (bf16_t)((v.w - mean) * rstd * gv.w + bv.w);
  reinterpret_cast<bf16x4*>(out + (size_t)row * kC)[t] = o;
}

// ---------------- GEMM: C[M,N] = A[M,K] @ Bt[N,K]^T  (both bf16, K-contig rows) --------
// EPI: 0 = bf16 out;  1 = f32 out + bias + residual add;  2 = bf16 out + bias + ReLU
template <int EPI>
__global__ __launch_bounds__(256, 2) void k_gemm_bt(
    const bf16_t* __restrict__ A, const bf16_t* __restrict__ Bt,
    const float* __restrict__ bias, const float* __restrict__ res,
    float* __restrict__ outf, bf16_t* __restrict__ outb, int M, int N, int K) {
  __shared__ bf16_t As[128 * 32];
  __shared__ bf16_t Bs[128 * 32];
  const int t = threadIdx.x;
  const int w = t >> 6, lane = t & 63;
  const int l15 = lane & 15, l4 = lane >> 4;
  const int m0 = blockIdx.y * 128, n0 = blockIdx.x * 128;
  const int wm = (w >> 1) * 64, wn = (w & 1) * 64;  // 2x2 wave grid, 64x64 per wave
  f32x4 acc[4][4] = {};

  // staging: thread t handles 16B at linear tile offset (r*256+t)*16, r in {0,1}
  const int srow = t >> 2;            // row within 64-row half
  const int scol = (t & 3) * 16;      // byte offset within 64B (=32 bf16) row
  const char* Ab = (const char*)A + ((size_t)(m0 + srow) * K) * 2 + scol;
  const char* Bb = (const char*)Bt + ((size_t)(n0 + srow) * K) * 2 + scol;
  const size_t rstep = (size_t)64 * K * 2;  // +64 rows in bytes
  char* AsB = (char*)As;
  char* BsB = (char*)Bs;

  for (int k0 = 0; k0 < K; k0 += 32) {
    const size_t kb = (size_t)k0 * 2;
    gload_lds16(Ab + kb,         AsB + w * 1024);
    gload_lds16(Ab + kb + rstep, AsB + 4096 + w * 1024);
    gload_lds16(Bb + kb,         BsB + w * 1024);
    gload_lds16(Bb + kb + rstep, BsB + 4096 + w * 1024);
    __syncthreads();  // drains vmcnt -> tiles visible
    bf16x8 af[4], bfr[4];
#pragma unroll
    for (int m = 0; m < 4; ++m)
      af[m] = *reinterpret_cast<const bf16x8*>(&As[(wm + m * 16 + l15) * 32 + l4 * 8]);
#pragma unroll
    for (int n = 0; n < 4; ++n)
      bfr[n] = *reinterpret_cast<const bf16x8*>(&Bs[(wn + n * 16 + l15) * 32 + l4 * 8]);
#pragma unroll
    for (int m = 0; m < 4; ++m)
#pragma unroll
      for (int n = 0; n < 4; ++n)
        acc[m][n] = mfma16(af[m], bfr[n], acc[m][n]);
    __syncthreads();  // protect LDS from next-iter staging
  }

  const int gm = m0 + wm + l4 * 4;
  const int gn = n0 + wn + l15;
  if constexpr (EPI == 0) {
#pragma unroll
    for (int m = 0; m < 4; ++m)
#pragma unroll
      for (int n = 0; n < 4; ++n)
#pragma unroll
        for (int r = 0; r < 4; ++r)
          outb[(size_t)(gm + m * 16 + r) * N + (gn + n * 16)] = (bf16_t)acc[m][n][r];
  } else if constexpr (EPI == 1) {
#pragma unroll
    for (int m = 0; m < 4; ++m)
#pragma unroll
      for (int n = 0; n < 4; ++n) {
        const int col = gn + n * 16;
        const float bv = bias[col];
#pragma unroll
        for (int r = 0; r < 4; ++r) {
          const size_t idx = (size_t)(gm + m * 16 + r) * N + col;
          outf[idx] = acc[m][n][r] + bv + res[idx];
        }
      }
  } else {
#pragma unroll
    for (int m = 0; m < 4; ++m)
#pragma unroll
      for (int n = 0; n < 4; ++n) {
        const int col = gn + n * 16;
        const float bv = bias[col];
#pragma unroll
        for (int r = 0; r < 4; ++r) {
          float v = acc[m][n][r] + bv;
          v = fmaxf(v, 0.f);
          outb[(size_t)(gm + m * 16 + r) * N + col] = (bf16_t)v;
        }
      }
  }
}

// ---------------- flash attention ----------------
// Q,K: [B*T, C] bf16 (head h in cols h*64..); Vt: [C][B*T] bf16 (pre-transposed);
// O: [B*T, C] bf16.  4 waves/block, each wave owns 16 q-rows, iterates 64-key tiles.
template <bool CAUSAL>
__global__ __launch_bounds__(256) void k_attn(const bf16_t* __restrict__ Q,
                                              const bf16_t* __restrict__ Kb,
                                              const bf16_t* __restrict__ Vt,
                                              bf16_t* __restrict__ O) {
  __shared__ bf16_t P[4][16][72];  // per-wave P buffer, 144B rows (16B aligned)
  const int qx = blockIdx.x, h = blockIdx.y, b = blockIdx.z;
  const int t = threadIdx.x, w = t >> 6, lane = t & 63;
  const int l15 = lane & 15, l4 = lane >> 4;
  const int qr0 = qx * 64 + w * 16;

  bf16x8 qf[2];
  {
    const bf16_t* qp = Q + (size_t)(b * kT + qr0 + l15) * kC + h * kHD + l4 * 8;
    qf[0] = *reinterpret_cast<const bf16x8*>(qp);
    qf[1] = *reinterpret_cast<const bf16x8*>(qp + 32);
#pragma unroll
    for (int j = 0; j < 8; ++j) {  // fold 1/sqrt(64) into Q (exact pow2 scale)
      qf[0][j] = (bf16_t)((float)qf[0][j] * 0.125f);
      qf[1][j] = (bf16_t)((float)qf[1][j] * 0.125f);
    }
  }
  f32x4 po[4] = {};
  float mrun[4], lrun[4];
#pragma unroll
  for (int r = 0; r < 4; ++r) { mrun[r] = -3.0e38f; lrun[r] = 0.f; }

  const int nkt = CAUSAL ? (qx + 1) : (kT / 64);
  for (int kt = 0; kt < nkt; ++kt) {
    f32x4 s[4] = {};
    const bf16_t* kp = Kb + (size_t)(b * kT + kt * 64 + l15) * kC + h * kHD + l4 * 8;
#pragma unroll
    for (int sub = 0; sub < 4; ++sub) {
      bf16x8 kf0 = *reinterpret_cast<const bf16x8*>(kp + (size_t)sub * 16 * kC);
      bf16x8 kf1 = *reinterpret_cast<const bf16x8*>(kp + (size_t)sub * 16 * kC + 32);
      s[sub] = mfma16(qf[0], kf0, s[sub]);
      s[sub] = mfma16(qf[1], kf1, s[sub]);
    }
    if (CAUSAL && kt == qx) {
#pragma unroll
      for (int sub = 0; sub < 4; ++sub)
#pragma unroll
        for (int r = 0; r < 4; ++r) {
          const int key = kt * 64 + sub * 16 + l15;
          const int qrow = qr0 + l4 * 4 + r;
          if (key > qrow) s[sub][r] = -3.0e38f;
        }
    }
    float corr[4];
#pragma unroll
    for (int r = 0; r < 4; ++r) {
      float v = fmaxf(fmaxf(s[0][r], s[1][r]), fmaxf(s[2][r], s[3][r]));
#pragma unroll
      for (int off = 1; off < 16; off <<= 1) v = fmaxf(v, __shfl_xor(v, off, 64));
      const float mnew = fmaxf(mrun[r], v);
      corr[r] = __expf(mrun[r] - mnew);
      mrun[r] = mnew;
    }
    float tsum[4];
#pragma unroll
    for (int r = 0; r < 4; ++r) tsum[r] = 0.f;
#pragma unroll
    for (int sub = 0; sub < 4; ++sub)
#pragma unroll
      for (int r = 0; r < 4; ++r) {
        const float p = __expf(s[sub][r] - mrun[r]);
        s[sub][r] = p;
        tsum[r] += p;
      }
#pragma unroll
    for (int r = 0; r < 4; ++r) {
      float v = tsum[r];
#pragma unroll
      for (int off = 1; off < 16; off <<= 1) v += __shfl_xor(v, off, 64);
      lrun[r] = lrun[r] * corr[r] + v;
    }
#pragma unroll
    for (int n = 0; n < 4; ++n)
#pragma unroll
      for (int r = 0; r < 4; ++r) po[n][r] *= corr[r];
    // P (D-layout) -> LDS -> re-read as A-operand layout
#pragma unroll
    for (int sub = 0; sub < 4; ++sub)
#pragma unroll
      for (int r = 0; r < 4; ++r)
        P[w][l4 * 4 + r][sub * 16 + l15] = (bf16_t)s[sub][r];
    __syncthreads();
#pragma unroll
    for (int kk = 0; kk < 2; ++kk) {
      bf16x8 pf = *reinterpret_cast<const bf16x8*>(&P[w][l15][kk * 32 + l4 * 8]);
#pragma unroll
      for (int n = 0; n < 4; ++n) {
        const bf16_t* vp = Vt + (size_t)(h * kHD + n * 16 + l15) * (kB * kT) +
                           (size_t)b * kT + kt * 64 + kk * 32 + l4 * 8;
        bf16x8 vf = *reinterpret_cast<const bf16x8*>(vp);
        po[n] = mfma16(pf, vf, po[n]);
      }
    }
    __syncthreads();
  }
  float inv[4];
#pragma unroll
  for (int r = 0; r < 4; ++r) inv[r] = 1.f / lrun[r];
#pragma unroll
  for (int n = 0; n < 4; ++n)
#pragma unroll
    for (int r = 0; r < 4; ++r)
      O[(size_t)(b * kT + qr0 + l4 * 4 + r) * kC + h * kHD + n * 16 + l15] =
          (bf16_t)(po[n][r] * inv[r]);
}

// ---------------- launcher ----------------
extern "C" void kernel_launch(void* const* d_in, const int* in_sizes, int n_in,
                              void* d_out, int out_size, void* d_ws, size_t ws_size,
                              hipStream_t stream) {
  const float* x      = (const float*)d_in[0];
  const float* enc    = (const float*)d_in[1];
  const float* sa_wq  = (const float*)d_in[2];
  const float* sa_wk  = (const float*)d_in[3];
  const float* sa_wv  = (const float*)d_in[4];
  const float* sa_pw  = (const float*)d_in[5];
  const float* sa_pb  = (const float*)d_in[6];
  const float* ca_wq  = (const float*)d_in[7];
  const float* ca_wk  = (const float*)d_in[8];
  const float* ca_wv  = (const float*)d_in[9];
  const float* ca_pw  = (const float*)d_in[10];
  const float* ca_pb  = (const float*)d_in[11];
  const float* ff_w1  = (const float*)d_in[12];
  const float* ff_b1  = (const float*)d_in[13];
  const float* ff_w2  = (const float*)d_in[14];
  const float* ff_b2  = (const float*)d_in[15];
  const float* ln1_g  = (const float*)d_in[16];
  const float* ln1_b  = (const float*)d_in[17];
  const float* ln2_g  = (const float*)d_in[18];
  const float* ln2_b  = (const float*)d_in[19];
  const float* ln3_g  = (const float*)d_in[20];
  const float* ln3_b  = (const float*)d_in[21];

  const size_t ACT_BF = (size_t)kM * kC * 2;   // 16 MiB
  const size_t ACT_F  = (size_t)kM * kC * 4;   // 32 MiB
  const size_t W_BF   = (size_t)kC * kC * 2;
  const size_t FF_BF  = (size_t)kC * kFF * 2;
  const size_t H_BF   = (size_t)kM * kFF * 2;

  char* ws = (char*)d_ws;
  size_t off = 0;
  auto alloc = [&](size_t bytes) {
    char* p = ws + off;
    off += (bytes + 255) & ~(size_t)255;
    return p;
  };
  bf16_t* xbf   = (bf16_t*)alloc(ACT_BF);
  bf16_t* encbf = (bf16_t*)alloc(ACT_BF);
  bf16_t* lnbuf = (bf16_t*)alloc(ACT_BF);
  bf16_t* wsaq  = (bf16_t*)alloc(W_BF);
  bf16_t* wsak  = (bf16_t*)alloc(W_BF);
  bf16_t* wsav  = (bf16_t*)alloc(W_BF);
  bf16_t* wsap  = (bf16_t*)alloc(W_BF);
  bf16_t* wcaq  = (bf16_t*)alloc(W_BF);
  bf16_t* wcak  = (bf16_t*)alloc(W_BF);
  bf16_t* wcav  = (bf16_t*)alloc(W_BF);
  bf16_t* wcap  = (bf16_t*)alloc(W_BF);
  bf16_t* wff1t = (bf16_t*)alloc(FF_BF);   // [4096][1024]
  bf16_t* wff2t = (bf16_t*)alloc(FF_BF);   // [1024][4096]
  float*  rbuf  = (float*)alloc(ACT_F);    // residual chain (f32)
  char*   scr   = alloc(5 * ACT_BF > H_BF ? 5 * ACT_BF : H_BF);
  bf16_t* qbf   = (bf16_t*)scr;
  bf16_t* kbf   = (bf16_t*)(scr + ACT_BF);
  bf16_t* vbf   = (bf16_t*)(scr + 2 * ACT_BF);
  bf16_t* vtbf  = (bf16_t*)(scr + 3 * ACT_BF);
  bf16_t* aobf  = (bf16_t*)(scr + 4 * ACT_BF);
  bf16_t* hbf   = (bf16_t*)scr;            // FFN hidden reuses q..ao region

  const dim3 blk256(256), blkT(32, 8);
  const int n4 = kM * kC / 4;
  const dim3 gGemmC(kC / 128, kM / 128);    // (8, 64)
  const dim3 gGemmF(kFF / 128, kM / 128);   // (32, 64)
  const dim3 gAttn(kT / 64, kH, kB);        // (16, 16, 8)

  // ---- input casts + weight transposes ----
  k_cast_bf16<<<n4 / 256, blk256, 0, stream>>>(x, xbf, n4);
  k_cast_bf16<<<n4 / 256, blk256, 0, stream>>>(enc, encbf, n4);
  k_transpose_cast<<<dim3(kC / 32, kC / 32), blkT, 0, stream>>>(sa_wq, wsaq, kC, kC);
  k_transpose_cast<<<dim3(kC / 32, kC / 32), blkT, 0, stream>>>(sa_wk, wsak, kC, kC);
  k_transpose_cast<<<dim3(kC / 32, kC / 32), blkT, 0, stream>>>(sa_wv, wsav, kC, kC);
  k_transpose_cast<<<dim3(kC / 32, kC / 32), blkT, 0, stream>>>(sa_pw, wsap, kC, kC);
  k_transpose_cast<<<dim3(kC / 32, kC / 32), blkT, 0, stream>>>(ca_wq, wcaq, kC, kC);
  k_transpose_cast<<<dim3(kC / 32, kC / 32), blkT, 0, stream>>>(ca_wk, wcak, kC, kC);
  k_transpose_cast<<<dim3(kC / 32, kC / 32), blkT, 0, stream>>>(ca_wv, wcav, kC, kC);
  k_transpose_cast<<<dim3(kC / 32, kC / 32), blkT, 0, stream>>>(ca_pw, wcap, kC, kC);
  k_transpose_cast<<<dim3(kFF / 32, kC / 32), blkT, 0, stream>>>(ff_w1, wff1t, kC, kFF);
  k_transpose_cast<<<dim3(kC / 32, kFF / 32), blkT, 0, stream>>>(ff_w2, wff2t, kFF, kC);

  // ---- self-attention (q from ln1(x), k/v from raw x, causal) ----
  k_ln<<<kM, blk256, 0, stream>>>(x, ln1_g, ln1_b, lnbuf);
  k_gemm_bt<0><<<gGemmC, blk256, 0, stream>>>(lnbuf, wsaq, nullptr, nullptr, nullptr, qbf, kM, kC, kC);
  k_gemm_bt<0><<<gGemmC, blk256, 0, stream>>>(xbf,   wsak, nullptr, nullptr, nullptr, kbf, kM, kC, kC);
  k_gemm_bt<0><<<gGemmC, blk256, 0, stream>>>(xbf,   wsav, nullptr, nullptr, nullptr, vbf, kM, kC, kC);
  k_transpose_bf16<<<dim3(kC / 32, kM / 32), blkT, 0, stream>>>(vbf, vtbf, kM, kC);
  k_attn<true><<<gAttn, blk256, 0, stream>>>(qbf, kbf, vtbf, aobf);
  k_gemm_bt<1><<<gGemmC, blk256, 0, stream>>>(aobf, wsap, sa_pb, x, rbuf, nullptr, kM, kC, kC);

  // ---- cross-attention (q from ln2(r), k/v from encoder_output) ----
  k_ln<<<kM, blk256, 0, stream>>>(rbuf, ln2_g, ln2_b, lnbuf);
  k_gemm_bt<0><<<gGemmC, blk256, 0, stream>>>(lnbuf, wcaq, nullptr, nullptr, nullptr, qbf, kM, kC, kC);
  k_gemm_bt<0><<<gGemmC, blk256, 0, stream>>>(encbf, wcak, nullptr, nullptr, nullptr, kbf, kM, kC, kC);
  k_gemm_bt<0><<<gGemmC, blk256, 0, stream>>>(encbf, wcav, nullptr, nullptr, nullptr, vbf, kM, kC, kC);
  k_transpose_bf16<<<dim3(kC / 32, kM / 32), blkT, 0, stream>>>(vbf, vtbf, kM, kC);
  k_attn<false><<<gAttn, blk256, 0, stream>>>(qbf, kbf, vtbf, aobf);
  k_gemm_bt<1><<<gGemmC, blk256, 0, stream>>>(aobf, wcap, ca_pb, rbuf, rbuf, nullptr, kM, kC, kC);

  // ---- feed-forward ----
  k_ln<<<kM, blk256, 0, stream>>>(rbuf, ln3_g, ln3_b, lnbuf);
  k_gemm_bt<2><<<gGemmF, blk256, 0, stream>>>(lnbuf, wff1t, ff_b1, nullptr, nullptr, hbf, kM, kFF, kC);
  k_gemm_bt<1><<<gGemmC, blk256, 0, stream>>>(hbf, wff2t, ff_b2, rbuf, (float*)d_out, nullptr, kM, kC, kFF);

  (void)in_sizes; (void)n_in; (void)out_size; (void)ws_size;
}

// Round 2
// 763.772 us; speedup vs baseline: 1.3516x; 1.3516x over previous
//
#include <hip/hip_runtime.h>
#include <stdint.h>
#include <stddef.h>

typedef __bf16 bf16_t;
typedef __bf16 bf16x4 __attribute__((ext_vector_type(4)));
typedef __bf16 bf16x8 __attribute__((ext_vector_type(8)));
typedef float f32x4 __attribute__((ext_vector_type(4)));

#define DEV static __device__ __forceinline__

static constexpr int kB = 8, kT = 1024, kC = 1024, kM = 8192, kH = 16, kHD = 64, kFF = 4096;

DEV f32x4 mfma16(bf16x8 a, bf16x8 b, f32x4 c) {
  return __builtin_amdgcn_mfma_f32_16x16x32_bf16(a, b, c, 0, 0, 0);
}

// async global->LDS, 16B per lane. LDS dest must be wave-uniform base (+lane*16 by HW).
DEV void gload_lds16(const void* g, void* l) {
  __builtin_amdgcn_global_load_lds(
      reinterpret_cast<const __attribute__((address_space(1))) void*>(
          reinterpret_cast<uintptr_t>(g)),
      reinterpret_cast<__attribute__((address_space(3))) void*>(
          static_cast<uint32_t>(reinterpret_cast<uintptr_t>(l))),
      16, 0, 0);
}

// ---------------- cast f32 -> bf16 ----------------
__global__ void k_cast_bf16(const float* __restrict__ in, bf16_t* __restrict__ out, int n4) {
  int i = blockIdx.x * blockDim.x + threadIdx.x;
  if (i >= n4) return;
  float4 v = reinterpret_cast<const float4*>(in)[i];
  bf16x4 o;
  o[0] = (bf16_t)v.x; o[1] = (bf16_t)v.y; o[2] = (bf16_t)v.z; o[3] = (bf16_t)v.w;
  reinterpret_cast<bf16x4*>(out)[i] = o;
}

// ---------- transpose+cast f32[R][C] -> bf16[C][R] ----------
__global__ void k_transpose_cast(const float* __restrict__ in, bf16_t* __restrict__ out,
                                 int R, int C) {
  __shared__ float tile[32][33];
  int c0 = blockIdx.x * 32, r0 = blockIdx.y * 32;
  int tx = threadIdx.x, ty = threadIdx.y;  // (32,8)
#pragma unroll
  for (int i = 0; i < 4; ++i)
    tile[ty + 8 * i][tx] = in[(size_t)(r0 + ty + 8 * i) * C + c0 + tx];
  __syncthreads();
#pragma unroll
  for (int i = 0; i < 4; ++i)
    out[(size_t)(c0 + ty + 8 * i) * R + r0 + tx] = (bf16_t)tile[tx][ty + 8 * i];
}

// ---------- transpose bf16[R][C] -> bf16[C][R] ----------
__global__ void k_transpose_bf16(const bf16_t* __restrict__ in, bf16_t* __restrict__ out,
                                 int R, int C) {
  __shared__ bf16_t tile[32][33];
  int c0 = blockIdx.x * 32, r0 = blockIdx.y * 32;
  int tx = threadIdx.x, ty = threadIdx.y;
#pragma unroll
  for (int i = 0; i < 4; ++i)
    tile[ty + 8 * i][tx] = in[(size_t)(r0 + ty + 8 * i) * C + c0 + tx];
  __syncthreads();
#pragma unroll
  for (int i = 0; i < 4; ++i)
    out[(size_t)(c0 + ty + 8 * i) * R + r0 + tx] = tile[tx][ty + 8 * i];
}

// ---------------- layernorm f32 -> bf16 (one block per row of 1024) ----------------
__global__ __launch_bounds__(256) void k_ln(const float* __restrict__ in,
                                            const float* __restrict__ g,
                                            const float* __restrict__ b,
                                            bf16_t* __restrict__ out) {
  int row = blockIdx.x, t = threadIdx.x;
  const float4 v = reinterpret_cast<const float4*>(in + (size_t)row * kC)[t];
  float s = v.x + v.y + v.z + v.w;
  float ss = v.x * v.x + v.y * v.y + v.z * v.z + v.w * v.w;
#pragma unroll
  for (int off = 1; off < 64; off <<= 1) {
    s += __shfl_xor(s, off, 64);
    ss += __shfl_xor(ss, off, 64);
  }
  __shared__ float rs[4], rss[4];
  int w = t >> 6;
  if ((t & 63) == 0) { rs[w] = s; rss[w] = ss; }
  __syncthreads();
  s = rs[0] + rs[1] + rs[2] + rs[3];
  ss = rss[0] + rss[1] + rss[2] + rss[3];
  float mean = s * (1.f / kC);
  float var = ss * (1.f / kC) - mean * mean;
  float rstd = rsqrtf(var + 1e-5f);
  float4 gv = reinterpret_cast<const float4*>(g)[t];
  float4 bv = reinterpret_cast<const float4*>(b)[t];
  bf16x4 o;
  o[0] = (bf16_t)((v.x - mean) * rstd * gv.x + bv.x);
  o[1] = (bf16_t)((v.y - mean) * rstd * gv.y + bv.y);
  o[2] = (bf16_t)((v.z - mean) * rstd * gv.z + bv.z);
  o[3] = (bf16_t)((v.w - mean) * rstd * gv.w + bv.w);
  reinterpret_cast<bf16x4*>(out + (size_t)row * kC)[t] = o;
}

// ---------------- GEMM: C[M,N] = A[M,K] @ Bt[N,K]^T  (both bf16, K-contig rows) --------
// EPI: 0 = bf16 out;  1 = f32 out + bias + residual add;  2 = bf16 out + bias + ReLU
template <int EPI>
__global__ __launch_bounds__(256, 2) void k_gemm_bt(
    const bf16_t* __restrict__ A, const bf16_t* __restrict__ Bt,
    const float* __restrict__ bias, const float* __restrict__ res,
    float* __restrict__ outf, bf16_t* __restrict__ outb, int M, int N, int K) {
  __shared__ bf16_t As[128 * 32];
  __shared__ bf16_t Bs[128 * 32];
  const int t = threadIdx.x;
  const int w = t >> 6, lane = t & 63;
  const int l15 = lane & 15, l4 = lane >> 4;
  const int m0 = blockIdx.y * 128, n0 = blockIdx.x * 128;
  const int wm = (w >> 1) * 64, wn = (w & 1) * 64;  // 2x2 wave grid, 64x64 per wave
  f32x4 acc[4][4] = {};

  // staging: thread t handles 16B at linear tile offset (r*256+t)*16, r in {0,1}
  const int srow = t >> 2;            // row within 64-row half
  const int scol = (t & 3) * 16;      // byte offset within 64B (=32 bf16) row
  const char* Ab = (const char*)A + ((size_t)(m0 + srow) * K) * 2 + scol;
  const char* Bb = (const char*)Bt + ((size_t)(n0 + srow) * K) * 2 + scol;
  const size_t rstep = (size_t)64 * K * 2;  // +64 rows in bytes
  char* AsB = (char*)As;
  char* BsB = (char*)Bs;

  for (int k0 = 0; k0 < K; k0 += 32) {
    const size_t kb = (size_t)k0 * 2;
    gload_lds16(Ab + kb,         AsB + w * 1024);
    gload_lds16(Ab + kb + rstep, AsB + 4096 + w * 1024);
    gload_lds16(Bb + kb,         BsB + w * 1024);
    gload_lds16(Bb + kb + rstep, BsB + 4096 + w * 1024);
    __syncthreads();  // drains vmcnt -> tiles visible
    bf16x8 af[4], bfr[4];
#pragma unroll
    for (int m = 0; m < 4; ++m)
      af[m] = *reinterpret_cast<const bf16x8*>(&As[(wm + m * 16 + l15) * 32 + l4 * 8]);
#pragma unroll
    for (int n = 0; n < 4; ++n)
      bfr[n] = *reinterpret_cast<const bf16x8*>(&Bs[(wn + n * 16 + l15) * 32 + l4 * 8]);
#pragma unroll
    for (int m = 0; m < 4; ++m)
#pragma unroll
      for (int n = 0; n < 4; ++n)
        acc[m][n] = mfma16(af[m], bfr[n], acc[m][n]);
    __syncthreads();  // protect LDS from next-iter staging
  }

  const int gm = m0 + wm + l4 * 4;
  const int gn = n0 + wn + l15;
  if constexpr (EPI == 0) {
#pragma unroll
    for (int m = 0; m < 4; ++m)
#pragma unroll
      for (int n = 0; n < 4; ++n)
#pragma unroll
        for (int r = 0; r < 4; ++r)
          outb[(size_t)(gm + m * 16 + r) * N + (gn + n * 16)] = (bf16_t)acc[m][n][r];
  } else if constexpr (EPI == 1) {
#pragma unroll
    for (int m = 0; m < 4; ++m)
#pragma unroll
      for (int n = 0; n < 4; ++n) {
        const int col = gn + n * 16;
        const float bv = bias[col];
#pragma unroll
        for (int r = 0; r < 4; ++r) {
          const size_t idx = (size_t)(gm + m * 16 + r) * N + col;
          outf[idx] = acc[m][n][r] + bv + res[idx];
        }
      }
  } else {
#pragma unroll
    for (int m = 0; m < 4; ++m)
#pragma unroll
      for (int n = 0; n < 4; ++n) {
        const int col = gn + n * 16;
        const float bv = bias[col];
#pragma unroll
        for (int r = 0; r < 4; ++r) {
          float v = acc[m][n][r] + bv;
          v = fmaxf(v, 0.f);
          outb[(size_t)(gm + m * 16 + r) * N + col] = (bf16_t)v;
        }
      }
  }
}

// ---------------- flash attention (swapped-operand, barrier-free) ----------------
// Q,K: [B*T, C] bf16 (head h in cols h*64..); Vt: [C][B*T] bf16 (pre-transposed);
// O: [B*T, C] bf16.
// 4 waves/block, each wave owns 32 q-rows (2 fragments), iterates 64-key tiles.
// S^T = mfma(K,Q): lane owns one q-row (l15) per fragment -> softmax state lane-local.
// O^T = mfma(V,P): output col = q-row (l15) -> rescale/normalize lane-local, no shfl.
template <bool CAUSAL>
__global__ __launch_bounds__(256) void k_attn(const bf16_t* __restrict__ Q,
                                              const bf16_t* __restrict__ Kb,
                                              const bf16_t* __restrict__ Vt,
                                              bf16_t* __restrict__ O) {
  __shared__ bf16_t P[4][32][72];  // per-wave P buffer: [q-row][key], 144B rows
  const int qx = blockIdx.x, h = blockIdx.y, b = blockIdx.z;
  const int t = threadIdx.x, w = t >> 6, lane = t & 63;
  const int l15 = lane & 15, l4 = lane >> 4;
  const int qr0 = qx * 128 + w * 32;  // this wave's first q-row

  // Q fragments (B-operand: row=l15=q-row, k=l4*8+j), scale 1/8 * log2(e) folded in.
  bf16x8 qf[2][2];
#pragma unroll
  for (int a = 0; a < 2; ++a) {
    const bf16_t* qp = Q + (size_t)(b * kT + qr0 + a * 16 + l15) * kC + h * kHD + l4 * 8;
    qf[a][0] = *reinterpret_cast<const bf16x8*>(qp);
    qf[a][1] = *reinterpret_cast<const bf16x8*>(qp + 32);
#pragma unroll
    for (int j = 0; j < 8; ++j) {
      qf[a][0][j] = (bf16_t)((float)qf[a][0][j] * 0.1803368801111204f);
      qf[a][1][j] = (bf16_t)((float)qf[a][1][j] * 0.1803368801111204f);
    }
  }
  f32x4 po[2][4] = {};          // O^T accum: po[a][n], row=d-in-chunk, col(l15)=q-row
  float mrun[2], lrun[2];
#pragma unroll
  for (int a = 0; a < 2; ++a) { mrun[a] = -3.0e38f; lrun[a] = 0.f; }

  const int nkt = CAUSAL ? (qr0 + 31) / 64 + 1 : (kT / 64);
  for (int kt = 0; kt < nkt; ++kt) {
    // K fragments (A-operand: row=l15=key) — issue first
    bf16x8 kf[4][2];
    const bf16_t* kp = Kb + (size_t)(b * kT + kt * 64 + l15) * kC + h * kHD + l4 * 8;
#pragma unroll
    for (int sub = 0; sub < 4; ++sub) {
      kf[sub][0] = *reinterpret_cast<const bf16x8*>(kp + (size_t)sub * 16 * kC);
      kf[sub][1] = *reinterpret_cast<const bf16x8*>(kp + (size_t)sub * 16 * kC + 32);
    }
    // V fragments — independent of softmax; issue early so latency hides under it
    bf16x8 vf[2][4];
#pragma unroll
    for (int kk = 0; kk < 2; ++kk)
#pragma unroll
      for (int n = 0; n < 4; ++n)
        vf[kk][n] = *reinterpret_cast<const bf16x8*>(
            Vt + (size_t)(h * kHD + n * 16 + l15) * (kB * kT) +
            (size_t)b * kT + kt * 64 + kk * 32 + l4 * 8);

    // S^T[key, q] : s[a][sub], col(l15)=q-row, row(l4*4+r)=key
    f32x4 s[2][4] = {};
#pragma unroll
    for (int a = 0; a < 2; ++a)
#pragma unroll
      for (int sub = 0; sub < 4; ++sub) {
        s[a][sub] = mfma16(kf[sub][0], qf[a][0], s[a][sub]);
        s[a][sub] = mfma16(kf[sub][1], qf[a][1], s[a][sub]);
      }
    if (CAUSAL && kt == nkt - 1) {
#pragma unroll
      for (int a = 0; a < 2; ++a) {
        const int qrow = qr0 + a * 16 + l15;
#pragma unroll
        for (int sub = 0; sub < 4; ++sub)
#pragma unroll
          for (int r = 0; r < 4; ++r) {
            const int key = kt * 64 + sub * 16 + l4 * 4 + r;
            if (key > qrow) s[a][sub][r] = -3.0e38f;
          }
      }
    }
#pragma unroll
    for (int a = 0; a < 2; ++a) {
      // in-lane max over 16 scores + 2 shfl over the l4 group
      float v = fmaxf(fmaxf(s[a][0][0], s[a][0][1]), fmaxf(s[a][0][2], s[a][0][3]));
#pragma unroll
      for (int sub = 1; sub < 4; ++sub)
#pragma unroll
        for (int r = 0; r < 4; ++r) v = fmaxf(v, s[a][sub][r]);
      v = fmaxf(v, __shfl_xor(v, 16, 64));
      v = fmaxf(v, __shfl_xor(v, 32, 64));
      const float mnew = fmaxf(mrun[a], v);
      const float corr = exp2f(mrun[a] - mnew);
      mrun[a] = mnew;
      // P = exp2(s - m), pack 4 per sub, store to per-wave LDS (8B writes)
      float tsum = 0.f;
#pragma unroll
      for (int sub = 0; sub < 4; ++sub) {
        bf16x4 pk;
#pragma unroll
        for (int r = 0; r < 4; ++r) {
          const float p = exp2f(s[a][sub][r] - mnew);
          tsum += p;
          pk[r] = (bf16_t)p;
        }
        *reinterpret_cast<bf16x4*>(&P[w][a * 16 + l15][sub * 16 + l4 * 4]) = pk;
      }
      tsum += __shfl_xor(tsum, 16, 64);
      tsum += __shfl_xor(tsum, 32, 64);
      lrun[a] = lrun[a] * corr + tsum;
      // rescale O^T accumulators (corr is per-q-row = per-lane here)
#pragma unroll
      for (int n = 0; n < 4; ++n)
#pragma unroll
        for (int r = 0; r < 4; ++r) po[a][n][r] *= corr;
    }
    // PV: O^T += V^T * P   (A=V^T frag, B=P frag; both row=l15 layouts)
#pragma unroll
    for (int a = 0; a < 2; ++a)
#pragma unroll
      for (int kk = 0; kk < 2; ++kk) {
        const bf16x8 pf =
            *reinterpret_cast<const bf16x8*>(&P[w][a * 16 + l15][kk * 32 + l4 * 8]);
#pragma unroll
        for (int n = 0; n < 4; ++n) po[a][n] = mfma16(vf[kk][n], pf, po[a][n]);
      }
  }
#pragma unroll
  for (int a = 0; a < 2; ++a) {
    const float inv = 1.f / lrun[a];
#pragma unroll
    for (int n = 0; n < 4; ++n) {
      bf16x4 ov;
#pragma unroll
      for (int r = 0; r < 4; ++r) ov[r] = (bf16_t)(po[a][n][r] * inv);
      *reinterpret_cast<bf16x4*>(
          O + (size_t)(b * kT + qr0 + a * 16 + l15) * kC + h * kHD + n * 16 + l4 * 4) = ov;
    }
  }
}

// ---------------- launcher ----------------
extern "C" void kernel_launch(void* const* d_in, const int* in_sizes, int n_in,
                              void* d_out, int out_size, void* d_ws, size_t ws_size,
                              hipStream_t stream) {
  const float* x      = (const float*)d_in[0];
  const float* enc    = (const float*)d_in[1];
  const float* sa_wq  = (const float*)d_in[2];
  const float* sa_wk  = (const float*)d_in[3];
  const float* sa_wv  = (const float*)d_in[4];
  const float* sa_pw  = (const float*)d_in[5];
  const float* sa_pb  = (const float*)d_in[6];
  const float* ca_wq  = (const float*)d_in[7];
  const float* ca_wk  = (const float*)d_in[8];
  const float* ca_wv  = (const float*)d_in[9];
  const float* ca_pw  = (const float*)d_in[10];
  const float* ca_pb  = (const float*)d_in[11];
  const float* ff_w1  = (const float*)d_in[12];
  const float* ff_b1  = (const float*)d_in[13];
  const float* ff_w2  = (const float*)d_in[14];
  const float* ff_b2  = (const float*)d_in[15];
  const float* ln1_g  = (const float*)d_in[16];
  const float* ln1_b  = (const float*)d_in[17];
  const float* ln2_g  = (const float*)d_in[18];
  const float* ln2_b  = (const float*)d_in[19];
  const float* ln3_g  = (const float*)d_in[20];
  const float* ln3_b  = (const float*)d_in[21];

  const size_t ACT_BF = (size_t)kM * kC * 2;   // 16 MiB
  const size_t ACT_F  = (size_t)kM * kC * 4;   // 32 MiB
  const size_t W_BF   = (size_t)kC * kC * 2;
  const size_t FF_BF  = (size_t)kC * kFF * 2;
  const size_t H_BF   = (size_t)kM * kFF * 2;

  char* ws = (char*)d_ws;
  size_t off = 0;
  auto alloc = [&](size_t bytes) {
    char* p = ws + off;
    off += (bytes + 255) & ~(size_t)255;
    return p;
  };
  bf16_t* xbf   = (bf16_t*)alloc(ACT_BF);
  bf16_t* encbf = (bf16_t*)alloc(ACT_BF);
  bf16_t* lnbuf = (bf16_t*)alloc(ACT_BF);
  bf16_t* wsaq  = (bf16_t*)alloc(W_BF);
  bf16_t* wsak  = (bf16_t*)alloc(W_BF);
  bf16_t* wsav  = (bf16_t*)alloc(W_BF);
  bf16_t* wsap  = (bf16_t*)alloc(W_BF);
  bf16_t* wcaq  = (bf16_t*)alloc(W_BF);
  bf16_t* wcak  = (bf16_t*)alloc(W_BF);
  bf16_t* wcav  = (bf16_t*)alloc(W_BF);
  bf16_t* wcap  = (bf16_t*)alloc(W_BF);
  bf16_t* wff1t = (bf16_t*)alloc(FF_BF);   // [4096][1024]
  bf16_t* wff2t = (bf16_t*)alloc(FF_BF);   // [1024][4096]
  float*  rbuf  = (float*)alloc(ACT_F);    // residual chain (f32)
  char*   scr   = alloc(5 * ACT_BF > H_BF ? 5 * ACT_BF : H_BF);
  bf16_t* qbf   = (bf16_t*)scr;
  bf16_t* kbf   = (bf16_t*)(scr + ACT_BF);
  bf16_t* vbf   = (bf16_t*)(scr + 2 * ACT_BF);
  bf16_t* vtbf  = (bf16_t*)(scr + 3 * ACT_BF);
  bf16_t* aobf  = (bf16_t*)(scr + 4 * ACT_BF);
  bf16_t* hbf   = (bf16_t*)scr;            // FFN hidden reuses q..ao region

  const dim3 blk256(256), blkT(32, 8);
  const int n4 = kM * kC / 4;
  const dim3 gGemmC(kC / 128, kM / 128);    // (8, 64)
  const dim3 gGemmF(kFF / 128, kM / 128);   // (32, 64)
  const dim3 gAttn(kT / 128, kH, kB);       // (8, 16, 8)

  // ---- input casts + weight transposes ----
  k_cast_bf16<<<n4 / 256, blk256, 0, stream>>>(x, xbf, n4);
  k_cast_bf16<<<n4 / 256, blk256, 0, stream>>>(enc, encbf, n4);
  k_transpose_cast<<<dim3(kC / 32, kC / 32), blkT, 0, stream>>>(sa_wq, wsaq, kC, kC);
  k_transpose_cast<<<dim3(kC / 32, kC / 32), blkT, 0, stream>>>(sa_wk, wsak, kC, kC);
  k_transpose_cast<<<dim3(kC / 32, kC / 32), blkT, 0, stream>>>(sa_wv, wsav, kC, kC);
  k_transpose_cast<<<dim3(kC / 32, kC / 32), blkT, 0, stream>>>(sa_pw, wsap, kC, kC);
  k_transpose_cast<<<dim3(kC / 32, kC / 32), blkT, 0, stream>>>(ca_wq, wcaq, kC, kC);
  k_transpose_cast<<<dim3(kC / 32, kC / 32), blkT, 0, stream>>>(ca_wk, wcak, kC, kC);
  k_transpose_cast<<<dim3(kC / 32, kC / 32), blkT, 0, stream>>>(ca_wv, wcav, kC, kC);
  k_transpose_cast<<<dim3(kC / 32, kC / 32), blkT, 0, stream>>>(ca_pw, wcap, kC, kC);
  k_transpose_cast<<<dim3(kFF / 32, kC / 32), blkT, 0, stream>>>(ff_w1, wff1t, kC, kFF);
  k_transpose_cast<<<dim3(kC / 32, kFF / 32), blkT, 0, stream>>>(ff_w2, wff2t, kFF, kC);

  // ---- self-attention (q from ln1(x), k/v from raw x, causal) ----
  k_ln<<<kM, blk256, 0, stream>>>(x, ln1_g, ln1_b, lnbuf);
  k_gemm_bt<0><<<gGemmC, blk256, 0, stream>>>(lnbuf, wsaq, nullptr, nullptr, nullptr, qbf, kM, kC, kC);
  k_gemm_bt<0><<<gGemmC, blk256, 0, stream>>>(xbf,   wsak, nullptr, nullptr, nullptr, kbf, kM, kC, kC);
  k_gemm_bt<0><<<gGemmC, blk256, 0, stream>>>(xbf,   wsav, nullptr, nullptr, nullptr, vbf, kM, kC, kC);
  k_transpose_bf16<<<dim3(kC / 32, kM / 32), blkT, 0, stream>>>(vbf, vtbf, kM, kC);
  k_attn<true><<<gAttn, blk256, 0, stream>>>(qbf, kbf, vtbf, aobf);
  k_gemm_bt<1><<<gGemmC, blk256, 0, stream>>>(aobf, wsap, sa_pb, x, rbuf, nullptr, kM, kC, kC);

  // ---- cross-attention (q from ln2(r), k/v from encoder_output) ----
  k_ln<<<kM, blk256, 0, stream>>>(rbuf, ln2_g, ln2_b, lnbuf);
  k_gemm_bt<0><<<gGemmC, blk256, 0, stream>>>(lnbuf, wcaq, nullptr, nullptr, nullptr, qbf, kM, kC, kC);
  k_gemm_bt<0><<<gGemmC, blk256, 0, stream>>>(encbf, wcak, nullptr, nullptr, nullptr, kbf, kM, kC, kC);
  k_gemm_bt<0><<<gGemmC, blk256, 0, stream>>>(encbf, wcav, nullptr, nullptr, nullptr, vbf, kM, kC, kC);
  k_transpose_bf16<<<dim3(kC / 32, kM / 32), blkT, 0, stream>>>(vbf, vtbf, kM, kC);
  k_attn<false><<<gAttn, blk256, 0, stream>>>(qbf, kbf, vtbf, aobf);
  k_gemm_bt<1><<<gGemmC, blk256, 0, stream>>>(aobf, wcap, ca_pb, rbuf, rbuf, nullptr, kM, kC, kC);

  // ---- feed-forward ----
  k_ln<<<kM, blk256, 0, stream>>>(rbuf, ln3_g, ln3_b, lnbuf);
  k_gemm_bt<2><<<gGemmF, blk256, 0, stream>>>(lnbuf, wff1t, ff_b1, nullptr, nullptr, hbf, kM, kFF, kC);
  k_gemm_bt<1><<<gGemmC, blk256, 0, stream>>>(hbf, wff2t, ff_b2, rbuf, (float*)d_out, nullptr, kM, kC, kFF);

  (void)in_sizes; (void)n_in; (void)out_size; (void)ws_size;
}

// Round 3
// 697.790 us; speedup vs baseline: 1.4794x; 1.0946x over previous
//
#include <hip/hip_runtime.h>
#include <stdint.h>
#include <stddef.h>

typedef __bf16 bf16_t;
typedef __bf16 bf16x4 __attribute__((ext_vector_type(4)));
typedef __bf16 bf16x8 __attribute__((ext_vector_type(8)));
typedef float f32x4 __attribute__((ext_vector_type(4)));

#define DEV static __device__ __forceinline__

static constexpr int kB = 8, kT = 1024, kC = 1024, kM = 8192, kH = 16, kHD = 64, kFF = 4096;

DEV f32x4 mfma16(bf16x8 a, bf16x8 b, f32x4 c) {
  return __builtin_amdgcn_mfma_f32_16x16x32_bf16(a, b, c, 0, 0, 0);
}

// async global->LDS, 16B per lane. LDS dest must be wave-uniform base (+lane*16 by HW).
DEV void gload_lds16(const void* g, void* l) {
  __builtin_amdgcn_global_load_lds(
      reinterpret_cast<const __attribute__((address_space(1))) void*>(
          reinterpret_cast<uintptr_t>(g)),
      reinterpret_cast<__attribute__((address_space(3))) void*>(
          static_cast<uint32_t>(reinterpret_cast<uintptr_t>(l))),
      16, 0, 0);
}

// ---------------- cast f32 -> bf16 ----------------
__global__ void k_cast_bf16(const float* __restrict__ in, bf16_t* __restrict__ out, int n4) {
  int i = blockIdx.x * blockDim.x + threadIdx.x;
  if (i >= n4) return;
  float4 v = reinterpret_cast<const float4*>(in)[i];
  bf16x4 o;
  o[0] = (bf16_t)v.x; o[1] = (bf16_t)v.y; o[2] = (bf16_t)v.z; o[3] = (bf16_t)v.w;
  reinterpret_cast<bf16x4*>(out)[i] = o;
}

// ---------- transpose+cast f32[R][C] -> bf16[C][R] ----------
__global__ void k_transpose_cast(const float* __restrict__ in, bf16_t* __restrict__ out,
                                 int R, int C) {
  __shared__ float tile[32][33];
  int c0 = blockIdx.x * 32, r0 = blockIdx.y * 32;
  int tx = threadIdx.x, ty = threadIdx.y;  // (32,8)
#pragma unroll
  for (int i = 0; i < 4; ++i)
    tile[ty + 8 * i][tx] = in[(size_t)(r0 + ty + 8 * i) * C + c0 + tx];
  __syncthreads();
#pragma unroll
  for (int i = 0; i < 4; ++i)
    out[(size_t)(c0 + ty + 8 * i) * R + r0 + tx] = (bf16_t)tile[tx][ty + 8 * i];
}

// ---------------- layernorm f32 -> bf16 (one block per row of 1024) ----------------
// CASTX: also emit bf16 cast of the raw input row (fuses k_cast of x).
template <bool CASTX>
__global__ __launch_bounds__(256) void k_ln(const float* __restrict__ in,
                                            const float* __restrict__ g,
                                            const float* __restrict__ b,
                                            bf16_t* __restrict__ out,
                                            bf16_t* __restrict__ rawout) {
  int row = blockIdx.x, t = threadIdx.x;
  const float4 v = reinterpret_cast<const float4*>(in + (size_t)row * kC)[t];
  if constexpr (CASTX) {
    bf16x4 c;
    c[0] = (bf16_t)v.x; c[1] = (bf16_t)v.y; c[2] = (bf16_t)v.z; c[3] = (bf16_t)v.w;
    reinterpret_cast<bf16x4*>(rawout + (size_t)row * kC)[t] = c;
  }
  float s = v.x + v.y + v.z + v.w;
  float ss = v.x * v.x + v.y * v.y + v.z * v.z + v.w * v.w;
#pragma unroll
  for (int off = 1; off < 64; off <<= 1) {
    s += __shfl_xor(s, off, 64);
    ss += __shfl_xor(ss, off, 64);
  }
  __shared__ float rs[4], rss[4];
  int w = t >> 6;
  if ((t & 63) == 0) { rs[w] = s; rss[w] = ss; }
  __syncthreads();
  s = rs[0] + rs[1] + rs[2] + rs[3];
  ss = rss[0] + rss[1] + rss[2] + rss[3];
  float mean = s * (1.f / kC);
  float var = ss * (1.f / kC) - mean * mean;
  float rstd = rsqrtf(var + 1e-5f);
  float4 gv = reinterpret_cast<const float4*>(g)[t];
  float4 bv = reinterpret_cast<const float4*>(b)[t];
  bf16x4 o;
  o[0] = (bf16_t)((v.x - mean) * rstd * gv.x + bv.x);
  o[1] = (bf16_t)((v.y - mean) * rstd * gv.y + bv.y);
  o[2] = (bf16_t)((v.z - mean) * rstd * gv.z + bv.z);
  o[3] = (bf16_t)((v.w - mean) * rstd * gv.w + bv.w);
  reinterpret_cast<bf16x4*>(out + (size_t)row * kC)[t] = o;
}

// ---------------- GEMM: C[M,N] = A[M,K] @ Bt[N,K]^T  (both bf16, K-contig rows) --------
// EPI: 0 = bf16 out; 1 = f32 out + bias + residual; 2 = bf16 out + bias + ReLU;
//      3 = bf16 TRANSPOSED out (out[c][tok], leading dim M) — for V^T
template <int EPI>
__global__ __launch_bounds__(256, 2) void k_gemm_bt(
    const bf16_t* __restrict__ A, const bf16_t* __restrict__ Bt,
    const float* __restrict__ bias, const float* __restrict__ res,
    float* __restrict__ outf, bf16_t* __restrict__ outb, int M, int N, int K) {
  __shared__ bf16_t As[128 * 32];
  __shared__ bf16_t Bs[128 * 32];
  const int t = threadIdx.x;
  const int w = t >> 6, lane = t & 63;
  const int l15 = lane & 15, l4 = lane >> 4;
  const int m0 = blockIdx.y * 128, n0 = blockIdx.x * 128;
  const int wm = (w >> 1) * 64, wn = (w & 1) * 64;  // 2x2 wave grid, 64x64 per wave
  f32x4 acc[4][4] = {};

  const int srow = t >> 2;            // row within 64-row half
  const int scol = (t & 3) * 16;      // byte offset within 64B (=32 bf16) row
  const char* Ab = (const char*)A + ((size_t)(m0 + srow) * K) * 2 + scol;
  const char* Bb = (const char*)Bt + ((size_t)(n0 + srow) * K) * 2 + scol;
  const size_t rstep = (size_t)64 * K * 2;  // +64 rows in bytes
  char* AsB = (char*)As;
  char* BsB = (char*)Bs;

  for (int k0 = 0; k0 < K; k0 += 32) {
    const size_t kb = (size_t)k0 * 2;
    gload_lds16(Ab + kb,         AsB + w * 1024);
    gload_lds16(Ab + kb + rstep, AsB + 4096 + w * 1024);
    gload_lds16(Bb + kb,         BsB + w * 1024);
    gload_lds16(Bb + kb + rstep, BsB + 4096 + w * 1024);
    __syncthreads();  // drains vmcnt -> tiles visible
    bf16x8 af[4], bfr[4];
#pragma unroll
    for (int m = 0; m < 4; ++m)
      af[m] = *reinterpret_cast<const bf16x8*>(&As[(wm + m * 16 + l15) * 32 + l4 * 8]);
#pragma unroll
    for (int n = 0; n < 4; ++n)
      bfr[n] = *reinterpret_cast<const bf16x8*>(&Bs[(wn + n * 16 + l15) * 32 + l4 * 8]);
#pragma unroll
    for (int m = 0; m < 4; ++m)
#pragma unroll
      for (int n = 0; n < 4; ++n)
        acc[m][n] = mfma16(af[m], bfr[n], acc[m][n]);
    __syncthreads();  // protect LDS from next-iter staging
  }

  const int gm = m0 + wm + l4 * 4;
  const int gn = n0 + wn + l15;
  if constexpr (EPI == 0) {
#pragma unroll
    for (int m = 0; m < 4; ++m)
#pragma unroll
      for (int n = 0; n < 4; ++n)
#pragma unroll
        for (int r = 0; r < 4; ++r)
          outb[(size_t)(gm + m * 16 + r) * N + (gn + n * 16)] = (bf16_t)acc[m][n][r];
  } else if constexpr (EPI == 1) {
#pragma unroll
    for (int m = 0; m < 4; ++m)
#pragma unroll
      for (int n = 0; n < 4; ++n) {
        const int col = gn + n * 16;
        const float bv = bias[col];
#pragma unroll
        for (int r = 0; r < 4; ++r) {
          const size_t idx = (size_t)(gm + m * 16 + r) * N + col;
          outf[idx] = acc[m][n][r] + bv + res[idx];
        }
      }
  } else if constexpr (EPI == 2) {
#pragma unroll
    for (int m = 0; m < 4; ++m)
#pragma unroll
      for (int n = 0; n < 4; ++n) {
        const int col = gn + n * 16;
        const float bv = bias[col];
#pragma unroll
        for (int r = 0; r < 4; ++r) {
          float v = acc[m][n][r] + bv;
          v = fmaxf(v, 0.f);
          outb[(size_t)(gm + m * 16 + r) * N + col] = (bf16_t)v;
        }
      }
  } else {  // EPI == 3: transposed bf16 store (rows of acc are contiguous in out)
#pragma unroll
    for (int m = 0; m < 4; ++m)
#pragma unroll
      for (int n = 0; n < 4; ++n) {
        bf16x4 ov;
#pragma unroll
        for (int r = 0; r < 4; ++r) ov[r] = (bf16_t)acc[m][n][r];
        *reinterpret_cast<bf16x4*>(&outb[(size_t)(gn + n * 16) * M + gm + m * 16]) = ov;
      }
  }
}

// ---------------- flash attention (swapped-operand, barrier-free) ----------------
// Grid relabeled (b, h, qx) so the 8 q-chunks sharing one (b,h)'s K/V get linear
// block ids differing by 128 -> same XCD (bid%8) -> K/V stays in one L2.
template <bool CAUSAL>
__global__ __launch_bounds__(256) void k_attn(const bf16_t* __restrict__ Q,
                                              const bf16_t* __restrict__ Kb,
                                              const bf16_t* __restrict__ Vt,
                                              bf16_t* __restrict__ O) {
  __shared__ bf16_t P[4][32][72];  // per-wave P buffer: [q-row][key], 144B rows
  const int b = blockIdx.x, h = blockIdx.y, qx = blockIdx.z;
  const int t = threadIdx.x, w = t >> 6, lane = t & 63;
  const int l15 = lane & 15, l4 = lane >> 4;
  const int qr0 = qx * 128 + w * 32;  // this wave's first q-row

  // Q fragments (B-operand: row=l15=q-row, k=l4*8+j), scale 1/8 * log2(e) folded in.
  bf16x8 qf[2][2];
#pragma unroll
  for (int a = 0; a < 2; ++a) {
    const bf16_t* qp = Q + (size_t)(b * kT + qr0 + a * 16 + l15) * kC + h * kHD + l4 * 8;
    qf[a][0] = *reinterpret_cast<const bf16x8*>(qp);
    qf[a][1] = *reinterpret_cast<const bf16x8*>(qp + 32);
#pragma unroll
    for (int j = 0; j < 8; ++j) {
      qf[a][0][j] = (bf16_t)((float)qf[a][0][j] * 0.1803368801111204f);
      qf[a][1][j] = (bf16_t)((float)qf[a][1][j] * 0.1803368801111204f);
    }
  }
  f32x4 po[2][4] = {};          // O^T accum: po[a][n], row=d-in-chunk, col(l15)=q-row
  float mrun[2], lrun[2];
#pragma unroll
  for (int a = 0; a < 2; ++a) { mrun[a] = -3.0e38f; lrun[a] = 0.f; }

  const int nkt = CAUSAL ? (qr0 + 31) / 64 + 1 : (kT / 64);
  // incremental per-lane base pointers
  const bf16_t* kp = Kb + (size_t)(b * kT + l15) * kC + h * kHD + l4 * 8;
  const bf16_t* vp = Vt + (size_t)(h * kHD + l15) * (kB * kT) + (size_t)b * kT + l4 * 8;

  for (int kt = 0; kt < nkt; ++kt, kp += (size_t)64 * kC, vp += 64) {
    // K fragments (A-operand: row=l15=key)
    bf16x8 kf[4][2];
#pragma unroll
    for (int sub = 0; sub < 4; ++sub) {
      kf[sub][0] = *reinterpret_cast<const bf16x8*>(kp + (size_t)sub * 16 * kC);
      kf[sub][1] = *reinterpret_cast<const bf16x8*>(kp + (size_t)sub * 16 * kC + 32);
    }
    // V fragments — independent of softmax; issue early so latency hides under it
    bf16x8 vf[2][4];
#pragma unroll
    for (int kk = 0; kk < 2; ++kk)
#pragma unroll
      for (int n = 0; n < 4; ++n)
        vf[kk][n] = *reinterpret_cast<const bf16x8*>(
            vp + (size_t)(n * 16) * (kB * kT) + kk * 32);

    // S^T[key, q] : s[a][sub], col(l15)=q-row, row(l4*4+r)=key
    f32x4 s[2][4] = {};
    __builtin_amdgcn_s_setprio(1);
#pragma unroll
    for (int a = 0; a < 2; ++a)
#pragma unroll
      for (int sub = 0; sub < 4; ++sub) {
        s[a][sub] = mfma16(kf[sub][0], qf[a][0], s[a][sub]);
        s[a][sub] = mfma16(kf[sub][1], qf[a][1], s[a][sub]);
      }
    __builtin_amdgcn_s_setprio(0);
    if (CAUSAL && kt == nkt - 1) {
#pragma unroll
      for (int a = 0; a < 2; ++a) {
        const int qrow = qr0 + a * 16 + l15;
#pragma unroll
        for (int sub = 0; sub < 4; ++sub)
#pragma unroll
          for (int r = 0; r < 4; ++r) {
            const int key = kt * 64 + sub * 16 + l4 * 4 + r;
            if (key > qrow) s[a][sub][r] = -3.0e38f;
          }
      }
    }
#pragma unroll
    for (int a = 0; a < 2; ++a) {
      // tree max (short dep chain) + 2 shfl over the l4 groups
      float t0 = fmaxf(fmaxf(s[a][0][0], s[a][0][1]), fmaxf(s[a][0][2], s[a][0][3]));
      float t1 = fmaxf(fmaxf(s[a][1][0], s[a][1][1]), fmaxf(s[a][1][2], s[a][1][3]));
      float t2 = fmaxf(fmaxf(s[a][2][0], s[a][2][1]), fmaxf(s[a][2][2], s[a][2][3]));
      float t3 = fmaxf(fmaxf(s[a][3][0], s[a][3][1]), fmaxf(s[a][3][2], s[a][3][3]));
      float v = fmaxf(fmaxf(t0, t1), fmaxf(t2, t3));
      v = fmaxf(v, __shfl_xor(v, 16, 64));
      v = fmaxf(v, __shfl_xor(v, 32, 64));
      // defer-max: only rescale when some row grew past m+8 (P bounded by 2^8)
      if (!__all(v <= mrun[a] + 8.f)) {
        const float mnew = fmaxf(mrun[a], v);
        const float corr = exp2f(mrun[a] - mnew);
        mrun[a] = mnew;
        lrun[a] *= corr;
#pragma unroll
        for (int n = 0; n < 4; ++n)
#pragma unroll
          for (int r = 0; r < 4; ++r) po[a][n][r] *= corr;
      }
      // P = exp2(s - m), pack 4 per sub, store to per-wave LDS (8B writes)
      float tsum = 0.f;
#pragma unroll
      for (int sub = 0; sub < 4; ++sub) {
        bf16x4 pk;
#pragma unroll
        for (int r = 0; r < 4; ++r) {
          const float p = exp2f(s[a][sub][r] - mrun[a]);
          tsum += p;
          pk[r] = (bf16_t)p;
        }
        *reinterpret_cast<bf16x4*>(&P[w][a * 16 + l15][sub * 16 + l4 * 4]) = pk;
      }
      tsum += __shfl_xor(tsum, 16, 64);
      tsum += __shfl_xor(tsum, 32, 64);
      lrun[a] += tsum;
    }
    // PV: O^T += V^T * P   (A=V^T frag, B=P frag; both row=l15 layouts)
#pragma unroll
    for (int a = 0; a < 2; ++a)
#pragma unroll
      for (int kk = 0; kk < 2; ++kk) {
        const bf16x8 pf =
            *reinterpret_cast<const bf16x8*>(&P[w][a * 16 + l15][kk * 32 + l4 * 8]);
        __builtin_amdgcn_s_setprio(1);
#pragma unroll
        for (int n = 0; n < 4; ++n) po[a][n] = mfma16(vf[kk][n], pf, po[a][n]);
        __builtin_amdgcn_s_setprio(0);
      }
  }
#pragma unroll
  for (int a = 0; a < 2; ++a) {
    const float inv = 1.f / lrun[a];
#pragma unroll
    for (int n = 0; n < 4; ++n) {
      bf16x4 ov;
#pragma unroll
      for (int r = 0; r < 4; ++r) ov[r] = (bf16_t)(po[a][n][r] * inv);
      *reinterpret_cast<bf16x4*>(
          O + (size_t)(b * kT + qr0 + a * 16 + l15) * kC + h * kHD + n * 16 + l4 * 4) = ov;
    }
  }
}

// ---------------- launcher ----------------
extern "C" void kernel_launch(void* const* d_in, const int* in_sizes, int n_in,
                              void* d_out, int out_size, void* d_ws, size_t ws_size,
                              hipStream_t stream) {
  const float* x      = (const float*)d_in[0];
  const float* enc    = (const float*)d_in[1];
  const float* sa_wq  = (const float*)d_in[2];
  const float* sa_wk  = (const float*)d_in[3];
  const float* sa_wv  = (const float*)d_in[4];
  const float* sa_pw  = (const float*)d_in[5];
  const float* sa_pb  = (const float*)d_in[6];
  const float* ca_wq  = (const float*)d_in[7];
  const float* ca_wk  = (const float*)d_in[8];
  const float* ca_wv  = (const float*)d_in[9];
  const float* ca_pw  = (const float*)d_in[10];
  const float* ca_pb  = (const float*)d_in[11];
  const float* ff_w1  = (const float*)d_in[12];
  const float* ff_b1  = (const float*)d_in[13];
  const float* ff_w2  = (const float*)d_in[14];
  const float* ff_b2  = (const float*)d_in[15];
  const float* ln1_g  = (const float*)d_in[16];
  const float* ln1_b  = (const float*)d_in[17];
  const float* ln2_g  = (const float*)d_in[18];
  const float* ln2_b  = (const float*)d_in[19];
  const float* ln3_g  = (const float*)d_in[20];
  const float* ln3_b  = (const float*)d_in[21];

  const size_t ACT_BF = (size_t)kM * kC * 2;   // 16 MiB
  const size_t ACT_F  = (size_t)kM * kC * 4;   // 32 MiB
  const size_t W_BF   = (size_t)kC * kC * 2;
  const size_t FF_BF  = (size_t)kC * kFF * 2;
  const size_t H_BF   = (size_t)kM * kFF * 2;

  char* ws = (char*)d_ws;
  size_t off = 0;
  auto alloc = [&](size_t bytes) {
    char* p = ws + off;
    off += (bytes + 255) & ~(size_t)255;
    return p;
  };
  bf16_t* xbf   = (bf16_t*)alloc(ACT_BF);
  bf16_t* encbf = (bf16_t*)alloc(ACT_BF);
  bf16_t* lnbuf = (bf16_t*)alloc(ACT_BF);
  bf16_t* wsaq  = (bf16_t*)alloc(W_BF);
  bf16_t* wsak  = (bf16_t*)alloc(W_BF);
  bf16_t* wsav  = (bf16_t*)alloc(W_BF);
  bf16_t* wsap  = (bf16_t*)alloc(W_BF);
  bf16_t* wcaq  = (bf16_t*)alloc(W_BF);
  bf16_t* wcak  = (bf16_t*)alloc(W_BF);
  bf16_t* wcav  = (bf16_t*)alloc(W_BF);
  bf16_t* wcap  = (bf16_t*)alloc(W_BF);
  bf16_t* wff1t = (bf16_t*)alloc(FF_BF);   // [4096][1024]
  bf16_t* wff2t = (bf16_t*)alloc(FF_BF);   // [1024][4096]
  float*  rbuf  = (float*)alloc(ACT_F);    // residual chain (f32)
  char*   scr   = alloc(5 * ACT_BF > H_BF ? 5 * ACT_BF : H_BF);
  bf16_t* qbf   = (bf16_t*)scr;
  bf16_t* kbf   = (bf16_t*)(scr + ACT_BF);
  bf16_t* vtbf  = (bf16_t*)(scr + 3 * ACT_BF);
  bf16_t* aobf  = (bf16_t*)(scr + 4 * ACT_BF);
  bf16_t* hbf   = (bf16_t*)scr;            // FFN hidden reuses q..ao region

  const dim3 blk256(256), blkT(32, 8);
  const int n4 = kM * kC / 4;
  const dim3 gGemmC(kC / 128, kM / 128);    // (8, 64)
  const dim3 gGemmF(kFF / 128, kM / 128);   // (32, 64)
  const dim3 gAttn(kB, kH, kT / 128);       // (8, 16, 8) — XCD-friendly order

  // ---- input casts + weight transposes ----
  k_cast_bf16<<<n4 / 256, blk256, 0, stream>>>(enc, encbf, n4);
  k_transpose_cast<<<dim3(kC / 32, kC / 32), blkT, 0, stream>>>(sa_wq, wsaq, kC, kC);
  k_transpose_cast<<<dim3(kC / 32, kC / 32), blkT, 0, stream>>>(sa_wk, wsak, kC, kC);
  k_transpose_cast<<<dim3(kC / 32, kC / 32), blkT, 0, stream>>>(sa_wv, wsav, kC, kC);
  k_transpose_cast<<<dim3(kC / 32, kC / 32), blkT, 0, stream>>>(sa_pw, wsap, kC, kC);
  k_transpose_cast<<<dim3(kC / 32, kC / 32), blkT, 0, stream>>>(ca_wq, wcaq, kC, kC);
  k_transpose_cast<<<dim3(kC / 32, kC / 32), blkT, 0, stream>>>(ca_wk, wcak, kC, kC);
  k_transpose_cast<<<dim3(kC / 32, kC / 32), blkT, 0, stream>>>(ca_wv, wcav, kC, kC);
  k_transpose_cast<<<dim3(kC / 32, kC / 32), blkT, 0, stream>>>(ca_pw, wcap, kC, kC);
  k_transpose_cast<<<dim3(kFF / 32, kC / 32), blkT, 0, stream>>>(ff_w1, wff1t, kC, kFF);
  k_transpose_cast<<<dim3(kC / 32, kFF / 32), blkT, 0, stream>>>(ff_w2, wff2t, kFF, kC);

  // ---- self-attention (q from ln1(x), k/v from raw x, causal) ----
  k_ln<true><<<kM, blk256, 0, stream>>>(x, ln1_g, ln1_b, lnbuf, xbf);
  k_gemm_bt<0><<<gGemmC, blk256, 0, stream>>>(lnbuf, wsaq, nullptr, nullptr, nullptr, qbf, kM, kC, kC);
  k_gemm_bt<0><<<gGemmC, blk256, 0, stream>>>(xbf,   wsak, nullptr, nullptr, nullptr, kbf, kM, kC, kC);
  k_gemm_bt<3><<<gGemmC, blk256, 0, stream>>>(xbf,   wsav, nullptr, nullptr, nullptr, vtbf, kM, kC, kC);
  k_attn<true><<<gAttn, blk256, 0, stream>>>(qbf, kbf, vtbf, aobf);
  k_gemm_bt<1><<<gGemmC, blk256, 0, stream>>>(aobf, wsap, sa_pb, x, rbuf, nullptr, kM, kC, kC);

  // ---- cross-attention (q from ln2(r), k/v from encoder_output) ----
  k_ln<false><<<kM, blk256, 0, stream>>>(rbuf, ln2_g, ln2_b, lnbuf, nullptr);
  k_gemm_bt<0><<<gGemmC, blk256, 0, stream>>>(lnbuf, wcaq, nullptr, nullptr, nullptr, qbf, kM, kC, kC);
  k_gemm_bt<0><<<gGemmC, blk256, 0, stream>>>(encbf, wcak, nullptr, nullptr, nullptr, kbf, kM, kC, kC);
  k_gemm_bt<3><<<gGemmC, blk256, 0, stream>>>(encbf, wcav, nullptr, nullptr, nullptr, vtbf, kM, kC, kC);
  k_attn<false><<<gAttn, blk256, 0, stream>>>(qbf, kbf, vtbf, aobf);
  k_gemm_bt<1><<<gGemmC, blk256, 0, stream>>>(aobf, wcap, ca_pb, rbuf, rbuf, nullptr, kM, kC, kC);

  // ---- feed-forward ----
  k_ln<false><<<kM, blk256, 0, stream>>>(rbuf, ln3_g, ln3_b, lnbuf, nullptr);
  k_gemm_bt<2><<<gGemmF, blk256, 0, stream>>>(lnbuf, wff1t, ff_b1, nullptr, nullptr, hbf, kM, kFF, kC);
  k_gemm_bt<1><<<gGemmC, blk256, 0, stream>>>(hbf, wff2t, ff_b2, rbuf, (float*)d_out, nullptr, kM, kC, kFF);

  (void)in_sizes; (void)n_in; (void)out_size; (void)ws_size;
}

// Round 4
// 693.690 us; speedup vs baseline: 1.4881x; 1.0059x over previous
//
#include <hip/hip_runtime.h>
#include <stdint.h>
#include <stddef.h>

typedef __bf16 bf16_t;
typedef __bf16 bf16x4 __attribute__((ext_vector_type(4)));
typedef __bf16 bf16x8 __attribute__((ext_vector_type(8)));
typedef float f32x4 __attribute__((ext_vector_type(4)));

#define DEV static __device__ __forceinline__

static constexpr int kB = 8, kT = 1024, kC = 1024, kM = 8192, kH = 16, kHD = 64, kFF = 4096;

DEV f32x4 mfma16(bf16x8 a, bf16x8 b, f32x4 c) {
  return __builtin_amdgcn_mfma_f32_16x16x32_bf16(a, b, c, 0, 0, 0);
}

// async global->LDS, 16B per lane. LDS dest must be wave-uniform base (+lane*16 by HW).
DEV void gload_lds16(const void* g, void* l) {
  __builtin_amdgcn_global_load_lds(
      reinterpret_cast<const __attribute__((address_space(1))) void*>(
          reinterpret_cast<uintptr_t>(g)),
      reinterpret_cast<__attribute__((address_space(3))) void*>(
          static_cast<uint32_t>(reinterpret_cast<uintptr_t>(l))),
      16, 0, 0);
}

// ---------------- cast f32 -> bf16 ----------------
__global__ void k_cast_bf16(const float* __restrict__ in, bf16_t* __restrict__ out, int n4) {
  int i = blockIdx.x * blockDim.x + threadIdx.x;
  if (i >= n4) return;
  float4 v = reinterpret_cast<const float4*>(in)[i];
  bf16x4 o;
  o[0] = (bf16_t)v.x; o[1] = (bf16_t)v.y; o[2] = (bf16_t)v.z; o[3] = (bf16_t)v.w;
  reinterpret_cast<bf16x4*>(out)[i] = o;
}

// ---------- transpose+cast f32[R][C] -> bf16[C][R] ----------
__global__ void k_transpose_cast(const float* __restrict__ in, bf16_t* __restrict__ out,
                                 int R, int C) {
  __shared__ float tile[32][33];
  int c0 = blockIdx.x * 32, r0 = blockIdx.y * 32;
  int tx = threadIdx.x, ty = threadIdx.y;  // (32,8)
#pragma unroll
  for (int i = 0; i < 4; ++i)
    tile[ty + 8 * i][tx] = in[(size_t)(r0 + ty + 8 * i) * C + c0 + tx];
  __syncthreads();
#pragma unroll
  for (int i = 0; i < 4; ++i)
    out[(size_t)(c0 + ty + 8 * i) * R + r0 + tx] = (bf16_t)tile[tx][ty + 8 * i];
}

// ---------------- layernorm f32 -> bf16 (one block per row of 1024) ----------------
// CASTX: also emit bf16 cast of the raw input row (fuses k_cast of x).
template <bool CASTX>
__global__ __launch_bounds__(256) void k_ln(const float* __restrict__ in,
                                            const float* __restrict__ g,
                                            const float* __restrict__ b,
                                            bf16_t* __restrict__ out,
                                            bf16_t* __restrict__ rawout) {
  int row = blockIdx.x, t = threadIdx.x;
  const float4 v = reinterpret_cast<const float4*>(in + (size_t)row * kC)[t];
  if constexpr (CASTX) {
    bf16x4 c;
    c[0] = (bf16_t)v.x; c[1] = (bf16_t)v.y; c[2] = (bf16_t)v.z; c[3] = (bf16_t)v.w;
    reinterpret_cast<bf16x4*>(rawout + (size_t)row * kC)[t] = c;
  }
  float s = v.x + v.y + v.z + v.w;
  float ss = v.x * v.x + v.y * v.y + v.z * v.z + v.w * v.w;
#pragma unroll
  for (int off = 1; off < 64; off <<= 1) {
    s += __shfl_xor(s, off, 64);
    ss += __shfl_xor(ss, off, 64);
  }
  __shared__ float rs[4], rss[4];
  int w = t >> 6;
  if ((t & 63) == 0) { rs[w] = s; rss[w] = ss; }
  __syncthreads();
  s = rs[0] + rs[1] + rs[2] + rs[3];
  ss = rss[0] + rss[1] + rss[2] + rss[3];
  float mean = s * (1.f / kC);
  float var = ss * (1.f / kC) - mean * mean;
  float rstd = rsqrtf(var + 1e-5f);
  float4 gv = reinterpret_cast<const float4*>(g)[t];
  float4 bv = reinterpret_cast<const float4*>(b)[t];
  bf16x4 o;
  o[0] = (bf16_t)((v.x - mean) * rstd * gv.x + bv.x);
  o[1] = (bf16_t)((v.y - mean) * rstd * gv.y + bv.y);
  o[2] = (bf16_t)((v.z - mean) * rstd * gv.z + bv.z);
  o[3] = (bf16_t)((v.w - mean) * rstd * gv.w + bv.w);
  reinterpret_cast<bf16x4*>(out + (size_t)row * kC)[t] = o;
}

// ---------------- GEMM: C[M,N] = A[M,K] @ Bt[N,K]^T  (both bf16, K-contig rows) --------
// EPI: 0 = bf16 out; 1 = f32 out + bias + residual; 2 = bf16 out + bias + ReLU;
//      3 = bf16 TRANSPOSED out (out[c][tok], leading dim M) — for V^T
template <int EPI>
__global__ __launch_bounds__(256, 2) void k_gemm_bt(
    const bf16_t* __restrict__ A, const bf16_t* __restrict__ Bt,
    const float* __restrict__ bias, const float* __restrict__ res,
    float* __restrict__ outf, bf16_t* __restrict__ outb, int M, int N, int K) {
  __shared__ bf16_t As[128 * 32];
  __shared__ bf16_t Bs[128 * 32];
  const int t = threadIdx.x;
  const int w = t >> 6, lane = t & 63;
  const int l15 = lane & 15, l4 = lane >> 4;
  const int m0 = blockIdx.y * 128, n0 = blockIdx.x * 128;
  const int wm = (w >> 1) * 64, wn = (w & 1) * 64;  // 2x2 wave grid, 64x64 per wave
  f32x4 acc[4][4] = {};

  const int srow = t >> 2;            // row within 64-row half
  const int scol = (t & 3) * 16;      // byte offset within 64B (=32 bf16) row
  const char* Ab = (const char*)A + ((size_t)(m0 + srow) * K) * 2 + scol;
  const char* Bb = (const char*)Bt + ((size_t)(n0 + srow) * K) * 2 + scol;
  const size_t rstep = (size_t)64 * K * 2;  // +64 rows in bytes
  char* AsB = (char*)As;
  char* BsB = (char*)Bs;

  for (int k0 = 0; k0 < K; k0 += 32) {
    const size_t kb = (size_t)k0 * 2;
    gload_lds16(Ab + kb,         AsB + w * 1024);
    gload_lds16(Ab + kb + rstep, AsB + 4096 + w * 1024);
    gload_lds16(Bb + kb,         BsB + w * 1024);
    gload_lds16(Bb + kb + rstep, BsB + 4096 + w * 1024);
    __syncthreads();  // drains vmcnt -> tiles visible
    bf16x8 af[4], bfr[4];
#pragma unroll
    for (int m = 0; m < 4; ++m)
      af[m] = *reinterpret_cast<const bf16x8*>(&As[(wm + m * 16 + l15) * 32 + l4 * 8]);
#pragma unroll
    for (int n = 0; n < 4; ++n)
      bfr[n] = *reinterpret_cast<const bf16x8*>(&Bs[(wn + n * 16 + l15) * 32 + l4 * 8]);
#pragma unroll
    for (int m = 0; m < 4; ++m)
#pragma unroll
      for (int n = 0; n < 4; ++n)
        acc[m][n] = mfma16(af[m], bfr[n], acc[m][n]);
    __syncthreads();  // protect LDS from next-iter staging
  }

  const int gm = m0 + wm + l4 * 4;
  const int gn = n0 + wn + l15;
  if constexpr (EPI == 0) {
#pragma unroll
    for (int m = 0; m < 4; ++m)
#pragma unroll
      for (int n = 0; n < 4; ++n)
#pragma unroll
        for (int r = 0; r < 4; ++r)
          outb[(size_t)(gm + m * 16 + r) * N + (gn + n * 16)] = (bf16_t)acc[m][n][r];
  } else if constexpr (EPI == 1) {
#pragma unroll
    for (int m = 0; m < 4; ++m)
#pragma unroll
      for (int n = 0; n < 4; ++n) {
        const int col = gn + n * 16;
        const float bv = bias[col];
#pragma unroll
        for (int r = 0; r < 4; ++r) {
          const size_t idx = (size_t)(gm + m * 16 + r) * N + col;
          outf[idx] = acc[m][n][r] + bv + res[idx];
        }
      }
  } else if constexpr (EPI == 2) {
#pragma unroll
    for (int m = 0; m < 4; ++m)
#pragma unroll
      for (int n = 0; n < 4; ++n) {
        const int col = gn + n * 16;
        const float bv = bias[col];
#pragma unroll
        for (int r = 0; r < 4; ++r) {
          float v = acc[m][n][r] + bv;
          v = fmaxf(v, 0.f);
          outb[(size_t)(gm + m * 16 + r) * N + col] = (bf16_t)v;
        }
      }
  } else {  // EPI == 3: transposed bf16 store (rows of acc are contiguous in out)
#pragma unroll
    for (int m = 0; m < 4; ++m)
#pragma unroll
      for (int n = 0; n < 4; ++n) {
        bf16x4 ov;
#pragma unroll
        for (int r = 0; r < 4; ++r) ov[r] = (bf16_t)acc[m][n][r];
        *reinterpret_cast<bf16x4*>(&outb[(size_t)(gn + n * 16) * M + gm + m * 16]) = ov;
      }
  }
}

// ---------------- flash attention (swapped-operand, single-wave blocks) ----------------
// Grid (b, h, qi): one 64-lane wave per block, 32 q-rows per wave, 64-key tiles.
// Linear block id mod 8 = b -> all q-chunks of one (b,h) on the same XCD (K/V L2-local).
// S^T = mfma(K,Q): lane owns one q-row per fragment -> softmax state lane-local.
// lrun kept as per-lane partial sums; cross-lane reduce deferred to the epilogue
// (valid: defer-max corr is uniform within each l4 group).
template <bool CAUSAL>
__global__ __launch_bounds__(64) void k_attn(const bf16_t* __restrict__ Q,
                                             const bf16_t* __restrict__ Kb,
                                             const bf16_t* __restrict__ Vt,
                                             bf16_t* __restrict__ O) {
  __shared__ bf16_t P[32][72];  // P buffer: [q-row][key], 144B rows
  const int b = blockIdx.x, h = blockIdx.y, qi = blockIdx.z;
  const int lane = threadIdx.x;
  const int l15 = lane & 15, l4 = lane >> 4;
  const int qr0 = qi * 32;  // this wave's first q-row

  // Q fragments (B-operand: row=l15=q-row, k=l4*8+j), scale 1/8 * log2(e) folded in.
  bf16x8 qf[2][2];
#pragma unroll
  for (int a = 0; a < 2; ++a) {
    const bf16_t* qp = Q + (size_t)(b * kT + qr0 + a * 16 + l15) * kC + h * kHD + l4 * 8;
    qf[a][0] = *reinterpret_cast<const bf16x8*>(qp);
    qf[a][1] = *reinterpret_cast<const bf16x8*>(qp + 32);
#pragma unroll
    for (int j = 0; j < 8; ++j) {
      qf[a][0][j] = (bf16_t)((float)qf[a][0][j] * 0.1803368801111204f);
      qf[a][1][j] = (bf16_t)((float)qf[a][1][j] * 0.1803368801111204f);
    }
  }
  f32x4 po[2][4] = {};          // O^T accum: po[a][n], row=d-in-chunk, col(l15)=q-row
  float mrun[2], lrun[2];
#pragma unroll
  for (int a = 0; a < 2; ++a) { mrun[a] = -3.0e38f; lrun[a] = 0.f; }

  const int nkt = CAUSAL ? (qr0 + 31) / 64 + 1 : (kT / 64);
  // incremental per-lane base pointers
  const bf16_t* kp = Kb + (size_t)(b * kT + l15) * kC + h * kHD + l4 * 8;
  const bf16_t* vp = Vt + (size_t)(h * kHD + l15) * (kB * kT) + (size_t)b * kT + l4 * 8;

  for (int kt = 0; kt < nkt; ++kt, kp += (size_t)64 * kC, vp += 64) {
    // K fragments (A-operand: row=l15=key)
    bf16x8 kf[4][2];
#pragma unroll
    for (int sub = 0; sub < 4; ++sub) {
      kf[sub][0] = *reinterpret_cast<const bf16x8*>(kp + (size_t)sub * 16 * kC);
      kf[sub][1] = *reinterpret_cast<const bf16x8*>(kp + (size_t)sub * 16 * kC + 32);
    }
    // S^T[key, q] : s[a][sub], col(l15)=q-row, row(l4*4+r)=key
    f32x4 s[2][4] = {};
    __builtin_amdgcn_s_setprio(1);
#pragma unroll
    for (int a = 0; a < 2; ++a)
#pragma unroll
      for (int sub = 0; sub < 4; ++sub) {
        s[a][sub] = mfma16(kf[sub][0], qf[a][0], s[a][sub]);
        s[a][sub] = mfma16(kf[sub][1], qf[a][1], s[a][sub]);
      }
    __builtin_amdgcn_s_setprio(0);
    // V fragments — independent of softmax; issue now so latency hides under it
    bf16x8 vf[2][4];
#pragma unroll
    for (int kk = 0; kk < 2; ++kk)
#pragma unroll
      for (int n = 0; n < 4; ++n)
        vf[kk][n] = *reinterpret_cast<const bf16x8*>(
            vp + (size_t)(n * 16) * (kB * kT) + kk * 32);
    if (CAUSAL && kt == nkt - 1) {
#pragma unroll
      for (int a = 0; a < 2; ++a) {
        const int qrow = qr0 + a * 16 + l15;
#pragma unroll
        for (int sub = 0; sub < 4; ++sub)
#pragma unroll
          for (int r = 0; r < 4; ++r) {
            const int key = kt * 64 + sub * 16 + l4 * 4 + r;
            if (key > qrow) s[a][sub][r] = -3.0e38f;
          }
      }
    }
#pragma unroll
    for (int a = 0; a < 2; ++a) {
      // tree max (short dep chain) + 2 shfl over the l4 groups
      float t0 = fmaxf(fmaxf(s[a][0][0], s[a][0][1]), fmaxf(s[a][0][2], s[a][0][3]));
      float t1 = fmaxf(fmaxf(s[a][1][0], s[a][1][1]), fmaxf(s[a][1][2], s[a][1][3]));
      float t2 = fmaxf(fmaxf(s[a][2][0], s[a][2][1]), fmaxf(s[a][2][2], s[a][2][3]));
      float t3 = fmaxf(fmaxf(s[a][3][0], s[a][3][1]), fmaxf(s[a][3][2], s[a][3][3]));
      float v = fmaxf(fmaxf(t0, t1), fmaxf(t2, t3));
      v = fmaxf(v, __shfl_xor(v, 16, 64));
      v = fmaxf(v, __shfl_xor(v, 32, 64));
      // defer-max: only rescale when some row grew past m+8 (P bounded by 2^8)
      if (!__all(v <= mrun[a] + 8.f)) {
        const float mnew = fmaxf(mrun[a], v);
        const float corr = exp2f(mrun[a] - mnew);
        mrun[a] = mnew;
        lrun[a] *= corr;
#pragma unroll
        for (int n = 0; n < 4; ++n)
#pragma unroll
          for (int r = 0; r < 4; ++r) po[a][n][r] *= corr;
      }
      // P = exp2(s - m), pack 4 per sub, store to LDS (8B writes); sum kept per-lane
#pragma unroll
      for (int sub = 0; sub < 4; ++sub) {
        bf16x4 pk;
#pragma unroll
        for (int r = 0; r < 4; ++r) {
          const float p = exp2f(s[a][sub][r] - mrun[a]);
          lrun[a] += p;
          pk[r] = (bf16_t)p;
        }
        *reinterpret_cast<bf16x4*>(&P[a * 16 + l15][sub * 16 + l4 * 4]) = pk;
      }
    }
    // PV: O^T += V^T * P   (A=V^T frag, B=P frag; both row=l15 layouts)
#pragma unroll
    for (int a = 0; a < 2; ++a)
#pragma unroll
      for (int kk = 0; kk < 2; ++kk) {
        const bf16x8 pf =
            *reinterpret_cast<const bf16x8*>(&P[a * 16 + l15][kk * 32 + l4 * 8]);
        __builtin_amdgcn_s_setprio(1);
#pragma unroll
        for (int n = 0; n < 4; ++n) po[a][n] = mfma16(vf[kk][n], pf, po[a][n]);
        __builtin_amdgcn_s_setprio(0);
      }
  }
#pragma unroll
  for (int a = 0; a < 2; ++a) {
    // deferred cross-lane sum reduce (per l4 group), then normalize
    float ltot = lrun[a];
    ltot += __shfl_xor(ltot, 16, 64);
    ltot += __shfl_xor(ltot, 32, 64);
    const float inv = 1.f / ltot;
#pragma unroll
    for (int n = 0; n < 4; ++n) {
      bf16x4 ov;
#pragma unroll
      for (int r = 0; r < 4; ++r) ov[r] = (bf16_t)(po[a][n][r] * inv);
      *reinterpret_cast<bf16x4*>(
          O + (size_t)(b * kT + qr0 + a * 16 + l15) * kC + h * kHD + n * 16 + l4 * 4) = ov;
    }
  }
}

// ---------------- launcher ----------------
extern "C" void kernel_launch(void* const* d_in, const int* in_sizes, int n_in,
                              void* d_out, int out_size, void* d_ws, size_t ws_size,
                              hipStream_t stream) {
  const float* x      = (const float*)d_in[0];
  const float* enc    = (const float*)d_in[1];
  const float* sa_wq  = (const float*)d_in[2];
  const float* sa_wk  = (const float*)d_in[3];
  const float* sa_wv  = (const float*)d_in[4];
  const float* sa_pw  = (const float*)d_in[5];
  const float* sa_pb  = (const float*)d_in[6];
  const float* ca_wq  = (const float*)d_in[7];
  const float* ca_wk  = (const float*)d_in[8];
  const float* ca_wv  = (const float*)d_in[9];
  const float* ca_pw  = (const float*)d_in[10];
  const float* ca_pb  = (const float*)d_in[11];
  const float* ff_w1  = (const float*)d_in[12];
  const float* ff_b1  = (const float*)d_in[13];
  const float* ff_w2  = (const float*)d_in[14];
  const float* ff_b2  = (const float*)d_in[15];
  const float* ln1_g  = (const float*)d_in[16];
  const float* ln1_b  = (const float*)d_in[17];
  const float* ln2_g  = (const float*)d_in[18];
  const float* ln2_b  = (const float*)d_in[19];
  const float* ln3_g  = (const float*)d_in[20];
  const float* ln3_b  = (const float*)d_in[21];

  const size_t ACT_BF = (size_t)kM * kC * 2;   // 16 MiB
  const size_t ACT_F  = (size_t)kM * kC * 4;   // 32 MiB
  const size_t W_BF   = (size_t)kC * kC * 2;
  const size_t FF_BF  = (size_t)kC * kFF * 2;
  const size_t H_BF   = (size_t)kM * kFF * 2;

  char* ws = (char*)d_ws;
  size_t off = 0;
  auto alloc = [&](size_t bytes) {
    char* p = ws + off;
    off += (bytes + 255) & ~(size_t)255;
    return p;
  };
  bf16_t* xbf   = (bf16_t*)alloc(ACT_BF);
  bf16_t* encbf = (bf16_t*)alloc(ACT_BF);
  bf16_t* lnbuf = (bf16_t*)alloc(ACT_BF);
  bf16_t* wsaq  = (bf16_t*)alloc(W_BF);
  bf16_t* wsak  = (bf16_t*)alloc(W_BF);
  bf16_t* wsav  = (bf16_t*)alloc(W_BF);
  bf16_t* wsap  = (bf16_t*)alloc(W_BF);
  bf16_t* wcaq  = (bf16_t*)alloc(W_BF);
  bf16_t* wcak  = (bf16_t*)alloc(W_BF);
  bf16_t* wcav  = (bf16_t*)alloc(W_BF);
  bf16_t* wcap  = (bf16_t*)alloc(W_BF);
  bf16_t* wff1t = (bf16_t*)alloc(FF_BF);   // [4096][1024]
  bf16_t* wff2t = (bf16_t*)alloc(FF_BF);   // [1024][4096]
  float*  rbuf  = (float*)alloc(ACT_F);    // residual chain (f32)
  char*   scr   = alloc(5 * ACT_BF > H_BF ? 5 * ACT_BF : H_BF);
  bf16_t* qbf   = (bf16_t*)scr;
  bf16_t* kbf   = (bf16_t*)(scr + ACT_BF);
  bf16_t* vtbf  = (bf16_t*)(scr + 3 * ACT_BF);
  bf16_t* aobf  = (bf16_t*)(scr + 4 * ACT_BF);
  bf16_t* hbf   = (bf16_t*)scr;            // FFN hidden reuses q..ao region

  const dim3 blk256(256), blk64(64), blkT(32, 8);
  const int n4 = kM * kC / 4;
  const dim3 gGemmC(kC / 128, kM / 128);    // (8, 64)
  const dim3 gGemmF(kFF / 128, kM / 128);   // (32, 64)
  const dim3 gAttn(kB, kH, kT / 32);        // (8, 16, 32) — 1 wave/block, XCD-friendly

  // ---- input casts + weight transposes ----
  k_cast_bf16<<<n4 / 256, blk256, 0, stream>>>(enc, encbf, n4);
  k_transpose_cast<<<dim3(kC / 32, kC / 32), blkT, 0, stream>>>(sa_wq, wsaq, kC, kC);
  k_transpose_cast<<<dim3(kC / 32, kC / 32), blkT, 0, stream>>>(sa_wk, wsak, kC, kC);
  k_transpose_cast<<<dim3(kC / 32, kC / 32), blkT, 0, stream>>>(sa_wv, wsav, kC, kC);
  k_transpose_cast<<<dim3(kC / 32, kC / 32), blkT, 0, stream>>>(sa_pw, wsap, kC, kC);
  k_transpose_cast<<<dim3(kC / 32, kC / 32), blkT, 0, stream>>>(ca_wq, wcaq, kC, kC);
  k_transpose_cast<<<dim3(kC / 32, kC / 32), blkT, 0, stream>>>(ca_wk, wcak, kC, kC);
  k_transpose_cast<<<dim3(kC / 32, kC / 32), blkT, 0, stream>>>(ca_wv, wcav, kC, kC);
  k_transpose_cast<<<dim3(kC / 32, kC / 32), blkT, 0, stream>>>(ca_pw, wcap, kC, kC);
  k_transpose_cast<<<dim3(kFF / 32, kC / 32), blkT, 0, stream>>>(ff_w1, wff1t, kC, kFF);
  k_transpose_cast<<<dim3(kC / 32, kFF / 32), blkT, 0, stream>>>(ff_w2, wff2t, kFF, kC);

  // ---- self-attention (q from ln1(x), k/v from raw x, causal) ----
  k_ln<true><<<kM, blk256, 0, stream>>>(x, ln1_g, ln1_b, lnbuf, xbf);
  k_gemm_bt<0><<<gGemmC, blk256, 0, stream>>>(lnbuf, wsaq, nullptr, nullptr, nullptr, qbf, kM, kC, kC);
  k_gemm_bt<0><<<gGemmC, blk256, 0, stream>>>(xbf,   wsak, nullptr, nullptr, nullptr, kbf, kM, kC, kC);
  k_gemm_bt<3><<<gGemmC, blk256, 0, stream>>>(xbf,   wsav, nullptr, nullptr, nullptr, vtbf, kM, kC, kC);
  k_attn<true><<<gAttn, blk64, 0, stream>>>(qbf, kbf, vtbf, aobf);
  k_gemm_bt<1><<<gGemmC, blk256, 0, stream>>>(aobf, wsap, sa_pb, x, rbuf, nullptr, kM, kC, kC);

  // ---- cross-attention (q from ln2(r), k/v from encoder_output) ----
  k_ln<false><<<kM, blk256, 0, stream>>>(rbuf, ln2_g, ln2_b, lnbuf, nullptr);
  k_gemm_bt<0><<<gGemmC, blk256, 0, stream>>>(lnbuf, wcaq, nullptr, nullptr, nullptr, qbf, kM, kC, kC);
  k_gemm_bt<0><<<gGemmC, blk256, 0, stream>>>(encbf, wcak, nullptr, nullptr, nullptr, kbf, kM, kC, kC);
  k_gemm_bt<3><<<gGemmC, blk256, 0, stream>>>(encbf, wcav, nullptr, nullptr, nullptr, vtbf, kM, kC, kC);
  k_attn<false><<<gAttn, blk64, 0, stream>>>(qbf, kbf, vtbf, aobf);
  k_gemm_bt<1><<<gGemmC, blk256, 0, stream>>>(aobf, wcap, ca_pb, rbuf, rbuf, nullptr, kM, kC, kC);

  // ---- feed-forward ----
  k_ln<false><<<kM, blk256, 0, stream>>>(rbuf, ln3_g, ln3_b, lnbuf, nullptr);
  k_gemm_bt<2><<<gGemmF, blk256, 0, stream>>>(lnbuf, wff1t, ff_b1, nullptr, nullptr, hbf, kM, kFF, kC);
  k_gemm_bt<1><<<gGemmC, blk256, 0, stream>>>(hbf, wff2t, ff_b2, rbuf, (float*)d_out, nullptr, kM, kC, kFF);

  (void)in_sizes; (void)n_in; (void)out_size; (void)ws_size;
}